// Round 7
// baseline (190.120 us; speedup 1.0000x reference)
//
#include <hip/hip_runtime.h>
#include <stdint.h>

#define KK 1000
#define NN 1000
#define MM 900000
#define QQ 225000            // points per stream; 4 streams per thread
#define FF 7
#define SENTINEL -9999.0f

// ---- macro repetition ------------------------------------------------------
#define R18(X) X(0) X(1) X(2) X(3) X(4) X(5) X(6) X(7) X(8) X(9) X(10) X(11) \
               X(12) X(13) X(14) X(15) X(16) X(17)
#define R36(X) R18(X) X(18) X(19) X(20) X(21) X(22) X(23) X(24) X(25) X(26) \
               X(27) X(28) X(29) X(30) X(31) X(32) X(33) X(34) X(35)

// ---------------- MLP + last-write-wins scatter -----------------------------
// R1-R5 (P=1, per-lane weight loads): VMEM-issue-bound (~2200 loads/wave vs
// 4.2k cyc FMA) -> VALUBusy 60%. R6 (LDS weights): LDS-pipe-bound (~12.8k cyc
// ds_read vs 8.4k FMA) + occupancy drop -> worse. This version: P=4 points
// per thread so each weight feeds 4 FMA chains, weights fetched as float2/
// float4 rows (~900 VMEM/wave ~= 3.6k cyc vs 17.6k cyc VALU -> VALU-bound).
__global__ __launch_bounds__(256, 2) void mlp_scatter(
    const float* __restrict__ in,    // [F][M]
    const int*   __restrict__ idx,   // [2][M]
    const float* __restrict__ w1, const float* __restrict__ b1,   // 18x7, 18
    const float* __restrict__ w2, const float* __restrict__ b2,   // 36x18, 36
    const float* __restrict__ w3, const float* __restrict__ b3,   // 36x36, 36
    const float* __restrict__ w4, const float* __restrict__ b4,   // 1x36, 1
    unsigned long long* __restrict__ grid)                        // K*N packed
{
    const float2* __restrict__ w2v = (const float2*)w2;  // rows: 9 float2 (8B-aligned)
    const float4* __restrict__ w3v = (const float4*)w3;  // rows: 9 float4 (16B-aligned)

    int t = blockIdx.x * 256 + threadIdx.x;
    if (t >= QQ) t = QQ - 1;          // tail lanes duplicate t=QQ-1: identical
    int m0 = t, m1 = t + QQ, m2 = t + 2 * QQ, m3 = t + 3 * QQ;  // packed atomics, idempotent

#define XL(f) float x##f##_0 = in[(f)*MM+m0], x##f##_1 = in[(f)*MM+m1], \
              x##f##_2 = in[(f)*MM+m2], x##f##_3 = in[(f)*MM+m3];
    XL(0) XL(1) XL(2) XL(3) XL(4) XL(5) XL(6)
#undef XL

#define T1(o,i) { float w = w1[(o)*7+(i)]; \
    a0=fmaf(w,x##i##_0,a0); a1=fmaf(w,x##i##_1,a1); \
    a2=fmaf(w,x##i##_2,a2); a3=fmaf(w,x##i##_3,a3); }
#define L1(o) float h1_##o##_0,h1_##o##_1,h1_##o##_2,h1_##o##_3; { \
    float a0=b1[o],a1=a0,a2=a0,a3=a0; \
    T1(o,0) T1(o,1) T1(o,2) T1(o,3) T1(o,4) T1(o,5) T1(o,6) \
    h1_##o##_0=fmaxf(a0,0.0f); h1_##o##_1=fmaxf(a1,0.0f); \
    h1_##o##_2=fmaxf(a2,0.0f); h1_##o##_3=fmaxf(a3,0.0f); }
    R18(L1)
#undef L1
#undef T1

#define T2(o,j,iA,iB) { float2 W = w2v[(o)*9+(j)]; \
    a0=fmaf(W.x,h1_##iA##_0,a0); a1=fmaf(W.x,h1_##iA##_1,a1); \
    a2=fmaf(W.x,h1_##iA##_2,a2); a3=fmaf(W.x,h1_##iA##_3,a3); \
    a0=fmaf(W.y,h1_##iB##_0,a0); a1=fmaf(W.y,h1_##iB##_1,a1); \
    a2=fmaf(W.y,h1_##iB##_2,a2); a3=fmaf(W.y,h1_##iB##_3,a3); }
#define L2(o) float h2_##o##_0,h2_##o##_1,h2_##o##_2,h2_##o##_3; { \
    float a0=b2[o],a1=a0,a2=a0,a3=a0; \
    T2(o,0,0,1) T2(o,1,2,3) T2(o,2,4,5) T2(o,3,6,7) T2(o,4,8,9) \
    T2(o,5,10,11) T2(o,6,12,13) T2(o,7,14,15) T2(o,8,16,17) \
    h2_##o##_0=fmaxf(a0,0.0f); h2_##o##_1=fmaxf(a1,0.0f); \
    h2_##o##_2=fmaxf(a2,0.0f); h2_##o##_3=fmaxf(a3,0.0f); }
    R36(L2)
#undef L2
#undef T2

    float v0 = b4[0], v1 = v0, v2 = v0, v3 = v0;
#define T3(o,j,iA,iB,iC,iD) { float4 W = w3v[(o)*9+(j)]; \
    a0=fmaf(W.x,h2_##iA##_0,a0); a1=fmaf(W.x,h2_##iA##_1,a1); \
    a2=fmaf(W.x,h2_##iA##_2,a2); a3=fmaf(W.x,h2_##iA##_3,a3); \
    a0=fmaf(W.y,h2_##iB##_0,a0); a1=fmaf(W.y,h2_##iB##_1,a1); \
    a2=fmaf(W.y,h2_##iB##_2,a2); a3=fmaf(W.y,h2_##iB##_3,a3); \
    a0=fmaf(W.z,h2_##iC##_0,a0); a1=fmaf(W.z,h2_##iC##_1,a1); \
    a2=fmaf(W.z,h2_##iC##_2,a2); a3=fmaf(W.z,h2_##iC##_3,a3); \
    a0=fmaf(W.w,h2_##iD##_0,a0); a1=fmaf(W.w,h2_##iD##_1,a1); \
    a2=fmaf(W.w,h2_##iD##_2,a2); a3=fmaf(W.w,h2_##iD##_3,a3); }
#define L34(o) { float a0=b3[o],a1=a0,a2=a0,a3=a0; \
    T3(o,0,0,1,2,3) T3(o,1,4,5,6,7) T3(o,2,8,9,10,11) T3(o,3,12,13,14,15) \
    T3(o,4,16,17,18,19) T3(o,5,20,21,22,23) T3(o,6,24,25,26,27) \
    T3(o,7,28,29,30,31) T3(o,8,32,33,34,35) \
    float w = w4[o]; \
    v0=fmaf(w,fmaxf(a0,0.0f),v0); v1=fmaf(w,fmaxf(a1,0.0f),v1); \
    v2=fmaf(w,fmaxf(a2,0.0f),v2); v3=fmaf(w,fmaxf(a3,0.0f),v3); }
    R36(L34)
#undef L34
#undef T3

    // high word = m+1 (unique, later m wins => numpy last-write-wins),
    // low word = value bits (payload only, never decides the compare)
    int r0i = idx[m0], c0i = idx[MM + m0];
    int r1i = idx[m1], c1i = idx[MM + m1];
    int r2i = idx[m2], c2i = idx[MM + m2];
    int r3i = idx[m3], c3i = idx[MM + m3];
    atomicMax(&grid[r0i * NN + c0i],
        ((unsigned long long)(unsigned)(m0 + 1) << 32) | (unsigned)__float_as_uint(v0));
    atomicMax(&grid[r1i * NN + c1i],
        ((unsigned long long)(unsigned)(m1 + 1) << 32) | (unsigned)__float_as_uint(v1));
    atomicMax(&grid[r2i * NN + c2i],
        ((unsigned long long)(unsigned)(m2 + 1) << 32) | (unsigned)__float_as_uint(v2));
    atomicMax(&grid[r3i * NN + c3i],
        ((unsigned long long)(unsigned)(m3 + 1) << 32) | (unsigned)__float_as_uint(v3));
}

// ---------------- row max: one block per row, single barrier ----------------
__global__ __launch_bounds__(256) void row_max_k(const unsigned long long* __restrict__ g,
                                                 float* __restrict__ out) {
    int r = blockIdx.x;
    float mx = SENTINEL;
    for (int c = threadIdx.x; c < NN; c += 256) {
        unsigned long long p = g[(size_t)r * NN + c];
        if (p) mx = fmaxf(mx, __uint_as_float((unsigned)p));
    }
    for (int s = 32; s > 0; s >>= 1) mx = fmaxf(mx, __shfl_down(mx, s, 64));
    __shared__ float red[4];
    if ((threadIdx.x & 63) == 0) red[threadIdx.x >> 6] = mx;
    __syncthreads();
    if (threadIdx.x == 0) out[r] = fmaxf(fmaxf(red[0], red[1]), fmaxf(red[2], red[3]));
}

// ---------------- col max: partials over row-chunks, then final -------------
#define CCHUNKS 25
#define CROWS   (KK / CCHUNKS)   // 40

__global__ __launch_bounds__(256) void col_partial(const unsigned long long* __restrict__ g,
                                                   float* __restrict__ part) {
    int n = blockIdx.x * 256 + threadIdx.x;
    if (n >= NN) return;
    int k0 = blockIdx.y * CROWS;
    float mx = SENTINEL;
    for (int k = k0; k < k0 + CROWS; ++k) {
        unsigned long long p = g[(size_t)k * NN + n];
        if (p) mx = fmaxf(mx, __uint_as_float((unsigned)p));
    }
    part[blockIdx.y * NN + n] = mx;
}

__global__ __launch_bounds__(256) void col_final(const float* __restrict__ part,
                                                 float* __restrict__ out) {
    int n = blockIdx.x * 256 + threadIdx.x;
    if (n >= NN) return;
    float mx = SENTINEL;
#pragma unroll
    for (int c = 0; c < CCHUNKS; ++c) mx = fmaxf(mx, part[c * NN + n]);
    out[KK + n] = mx;
}

extern "C" void kernel_launch(void* const* d_in, const int* in_sizes, int n_in,
                              void* d_out, int out_size, void* d_ws, size_t ws_size,
                              hipStream_t stream) {
    const float* in  = (const float*)d_in[0];
    // d_in[1] = T_out (zeros) — unused
    const int*   idx = (const int*)d_in[2];
    const float* w1  = (const float*)d_in[3];
    const float* b1  = (const float*)d_in[4];
    const float* w2  = (const float*)d_in[5];
    const float* b2  = (const float*)d_in[6];
    const float* w3  = (const float*)d_in[7];
    const float* b3  = (const float*)d_in[8];
    const float* w4  = (const float*)d_in[9];
    const float* b4  = (const float*)d_in[10];

    unsigned long long* grid = (unsigned long long*)d_ws;            // 8 MB
    float* part = (float*)((char*)d_ws + (size_t)KK * NN * 8);       // 100 KB
    float* out  = (float*)d_out;

    // zero the packed grid via DMA (ws is re-poisoned 0xAA before every launch)
    hipMemsetAsync(grid, 0, (size_t)KK * NN * 8, stream);

    mlp_scatter<<<(QQ + 255) / 256, 256, 0, stream>>>(
        in, idx, w1, b1, w2, b2, w3, b3, w4, b4, grid);

    row_max_k<<<KK, 256, 0, stream>>>(grid, out);
    col_partial<<<dim3(4, CCHUNKS), 256, 0, stream>>>(grid, part);
    col_final<<<4, 256, 0, stream>>>(part, out);
}

// Round 8
// 177.984 us; speedup vs baseline: 1.0682x; 1.0682x over previous
//
#include <hip/hip_runtime.h>
#include <stdint.h>

#define KK 1000
#define NN 1000
#define MM 900000
#define HALF 450000          // points per stream; 2 streams per thread
#define FF 7
#define SENTINEL -9999.0f

// ---- macro repetition ------------------------------------------------------
#define R18(X) X(0) X(1) X(2) X(3) X(4) X(5) X(6) X(7) X(8) X(9) X(10) X(11) \
               X(12) X(13) X(14) X(15) X(16) X(17)
#define R36(X) R18(X) X(18) X(19) X(20) X(21) X(22) X(23) X(24) X(25) X(26) \
               X(27) X(28) X(29) X(30) X(31) X(32) X(33) X(34) X(35)

// ---------------- MLP + last-write-wins scatter -----------------------------
// History: R1-R5 (P=1) VMEM-issue-bound, VGPR=32 via backend spill; R6 (LDS)
// LDS-pipe-bound; R7 (P=4) live set ~230 >> budget -> spill + scratch-limited
// occupancy (20%). Root cause: allocator's occupancy heuristic picks a small
// VGPR budget and spills named values. amdgpu_waves_per_eu(4,4) pins the
// budget to 128 VGPRs; P=2's live set (~115) fits -> no spill, and each
// weight load feeds 2 FMA chains (~880 VMEM instrs vs 8.4k cyc FMA issue).
__global__ __attribute__((amdgpu_waves_per_eu(4, 4))) __launch_bounds__(256)
void mlp_scatter(
    const float* __restrict__ in,    // [F][M]
    const int*   __restrict__ idx,   // [2][M]
    const float* __restrict__ w1, const float* __restrict__ b1,   // 18x7, 18
    const float* __restrict__ w2, const float* __restrict__ b2,   // 36x18, 36
    const float* __restrict__ w3, const float* __restrict__ b3,   // 36x36, 36
    const float* __restrict__ w4, const float* __restrict__ b4,   // 1x36, 1
    unsigned long long* __restrict__ grid)                        // K*N packed
{
    const float2* __restrict__ w2v = (const float2*)w2;  // rows: 9 float2 (8B-aligned)
    const float4* __restrict__ w3v = (const float4*)w3;  // rows: 9 float4 (16B-aligned)

    int t = blockIdx.x * 256 + threadIdx.x;
    if (t >= HALF) t = HALF - 1;      // tail lanes duplicate t=HALF-1: identical
    int m0 = t, m1 = t + HALF;        // packed atomics, idempotent.

#define XL(f) float x##f##_0 = in[(f)*MM+m0], x##f##_1 = in[(f)*MM+m1];
    XL(0) XL(1) XL(2) XL(3) XL(4) XL(5) XL(6)
#undef XL

#define T1(o,i) { float w = w1[(o)*7+(i)]; \
    a0=fmaf(w,x##i##_0,a0); a1=fmaf(w,x##i##_1,a1); }
#define L1(o) float h1_##o##_0,h1_##o##_1; { \
    float a0=b1[o],a1=a0; \
    T1(o,0) T1(o,1) T1(o,2) T1(o,3) T1(o,4) T1(o,5) T1(o,6) \
    h1_##o##_0=fmaxf(a0,0.0f); h1_##o##_1=fmaxf(a1,0.0f); }
    R18(L1)
#undef L1
#undef T1

#define T2(o,j,iA,iB) { float2 W = w2v[(o)*9+(j)]; \
    a0=fmaf(W.x,h1_##iA##_0,a0); a1=fmaf(W.x,h1_##iA##_1,a1); \
    a0=fmaf(W.y,h1_##iB##_0,a0); a1=fmaf(W.y,h1_##iB##_1,a1); }
#define L2(o) float h2_##o##_0,h2_##o##_1; { \
    float a0=b2[o],a1=a0; \
    T2(o,0,0,1) T2(o,1,2,3) T2(o,2,4,5) T2(o,3,6,7) T2(o,4,8,9) \
    T2(o,5,10,11) T2(o,6,12,13) T2(o,7,14,15) T2(o,8,16,17) \
    h2_##o##_0=fmaxf(a0,0.0f); h2_##o##_1=fmaxf(a1,0.0f); }
    R36(L2)
#undef L2
#undef T2

    float v0 = b4[0], v1 = v0;
#define T3(o,j,iA,iB,iC,iD) { float4 W = w3v[(o)*9+(j)]; \
    a0=fmaf(W.x,h2_##iA##_0,a0); a1=fmaf(W.x,h2_##iA##_1,a1); \
    a0=fmaf(W.y,h2_##iB##_0,a0); a1=fmaf(W.y,h2_##iB##_1,a1); \
    a0=fmaf(W.z,h2_##iC##_0,a0); a1=fmaf(W.z,h2_##iC##_1,a1); \
    a0=fmaf(W.w,h2_##iD##_0,a0); a1=fmaf(W.w,h2_##iD##_1,a1); }
#define L34(o) { float a0=b3[o],a1=a0; \
    T3(o,0,0,1,2,3) T3(o,1,4,5,6,7) T3(o,2,8,9,10,11) T3(o,3,12,13,14,15) \
    T3(o,4,16,17,18,19) T3(o,5,20,21,22,23) T3(o,6,24,25,26,27) \
    T3(o,7,28,29,30,31) T3(o,8,32,33,34,35) \
    float w = w4[o]; \
    v0=fmaf(w,fmaxf(a0,0.0f),v0); v1=fmaf(w,fmaxf(a1,0.0f),v1); }
    R36(L34)
#undef L34
#undef T3

    int r0i = idx[m0], c0i = idx[MM + m0];
    int r1i = idx[m1], c1i = idx[MM + m1];
    // high word = m+1 (unique, later m wins => numpy last-write-wins),
    // low word = value bits (payload only, never decides the compare)
    atomicMax(&grid[r0i * NN + c0i],
        ((unsigned long long)(unsigned)(m0 + 1) << 32) | (unsigned)__float_as_uint(v0));
    atomicMax(&grid[r1i * NN + c1i],
        ((unsigned long long)(unsigned)(m1 + 1) << 32) | (unsigned)__float_as_uint(v1));
}

// ---------------- row max: one block per row, single barrier ----------------
__global__ __launch_bounds__(256) void row_max_k(const unsigned long long* __restrict__ g,
                                                 float* __restrict__ out) {
    int r = blockIdx.x;
    float mx = SENTINEL;
    for (int c = threadIdx.x; c < NN; c += 256) {
        unsigned long long p = g[(size_t)r * NN + c];
        if (p) mx = fmaxf(mx, __uint_as_float((unsigned)p));
    }
    for (int s = 32; s > 0; s >>= 1) mx = fmaxf(mx, __shfl_down(mx, s, 64));
    __shared__ float red[4];
    if ((threadIdx.x & 63) == 0) red[threadIdx.x >> 6] = mx;
    __syncthreads();
    if (threadIdx.x == 0) out[r] = fmaxf(fmaxf(red[0], red[1]), fmaxf(red[2], red[3]));
}

// ---------------- col max: partials over row-chunks, then final -------------
#define CCHUNKS 25
#define CROWS   (KK / CCHUNKS)   // 40

__global__ __launch_bounds__(256) void col_partial(const unsigned long long* __restrict__ g,
                                                   float* __restrict__ part) {
    int n = blockIdx.x * 256 + threadIdx.x;
    if (n >= NN) return;
    int k0 = blockIdx.y * CROWS;
    float mx = SENTINEL;
    for (int k = k0; k < k0 + CROWS; ++k) {
        unsigned long long p = g[(size_t)k * NN + n];
        if (p) mx = fmaxf(mx, __uint_as_float((unsigned)p));
    }
    part[blockIdx.y * NN + n] = mx;
}

__global__ __launch_bounds__(256) void col_final(const float* __restrict__ part,
                                                 float* __restrict__ out) {
    int n = blockIdx.x * 256 + threadIdx.x;
    if (n >= NN) return;
    float mx = SENTINEL;
#pragma unroll
    for (int c = 0; c < CCHUNKS; ++c) mx = fmaxf(mx, part[c * NN + n]);
    out[KK + n] = mx;
}

extern "C" void kernel_launch(void* const* d_in, const int* in_sizes, int n_in,
                              void* d_out, int out_size, void* d_ws, size_t ws_size,
                              hipStream_t stream) {
    const float* in  = (const float*)d_in[0];
    // d_in[1] = T_out (zeros) — unused
    const int*   idx = (const int*)d_in[2];
    const float* w1  = (const float*)d_in[3];
    const float* b1  = (const float*)d_in[4];
    const float* w2  = (const float*)d_in[5];
    const float* b2  = (const float*)d_in[6];
    const float* w3  = (const float*)d_in[7];
    const float* b3  = (const float*)d_in[8];
    const float* w4  = (const float*)d_in[9];
    const float* b4  = (const float*)d_in[10];

    unsigned long long* grid = (unsigned long long*)d_ws;            // 8 MB
    float* part = (float*)((char*)d_ws + (size_t)KK * NN * 8);       // 100 KB
    float* out  = (float*)d_out;

    // zero the packed grid via DMA (ws is re-poisoned 0xAA before every launch)
    hipMemsetAsync(grid, 0, (size_t)KK * NN * 8, stream);

    mlp_scatter<<<(HALF + 255) / 256, 256, 0, stream>>>(
        in, idx, w1, b1, w2, b2, w3, b3, w4, b4, grid);

    row_max_k<<<KK, 256, 0, stream>>>(grid, out);
    col_partial<<<dim3(4, CCHUNKS), 256, 0, stream>>>(grid, part);
    col_final<<<4, 256, 0, stream>>>(part, out);
}